// Round 24
// baseline (56.711 us; speedup 1.0000x reference)
//
#include <hip/hip_runtime.h>
#include <stdint.h>

static constexpr int   Bn      = 32;
static constexpr int   Tn      = 2000;
static constexpr int   Hn      = 512;
static constexpr int   Ln      = 256;     // max_label_len
static constexpr float kThresh = 0.95f;
static constexpr int   TCHUNK  = 40;      // meta granularity (consumer chunk)
static constexpr int   NTCH    = Tn / TCHUNK;   // 50
static constexpr int   CSPLIT  = 4;       // consumer blocks per (tc, b)
static constexpr int   MSTRIDE = 64;            // meta entries per row (padded)
static constexpr unsigned PUBF = 0x40000000u;   // published flag (low word)

// ---------------------------------------------------------------------------
// Fused producer-consumer CIF. R24 = R23 with the two proven latency levers
// pushed further (R23: occupancy 13.5->26%, total 65->56 us):
//   CSPLIT 2->4 (6400 consumer waves; each block owns H/4 = 128 floats as
//   lane x float2, coalesced 512 B per wave instruction), and
//   prefetch depth 2->4 (rotation of 4 named float2; h[t+4] issues before
//   h[t] is consumed -> 4 loads in flight per wave).
// Consumer phase is latency-bound (per-step compute ~10 cyc vs ~400 cyc
// load), so exposed-latency ~ 1/(waves x loads-in-flight): ~4x R23.
//
// Producer (blocks 0..31): R22 verbatim -- LDS-staged row, depth-5 rotation
// of named float4 (no vmem, no arrays in the serial chain), meta published
// every 40 steps as ONE relaxed 8-B atomic (meta IS the flag).
// Consumers: exclusive ownership of segments CLOSING in chunk tc, walk-back
// re-derives the straddler opening, ascending-t accumulation (absmax 0.0 in
// R18-R23), tc=NTCH-1 zero-fills [fc,256). No atomics, no pre-zero pass.
// ---------------------------------------------------------------------------
__global__ __launch_bounds__(64, 1) void cif_fused_kernel(
    const float* __restrict__ hidden,
    const float* __restrict__ alphas,
    uint64_t* __restrict__ meta,     // [Bn*MSTRIDE]
    float* __restrict__ out) {
  const int lane = threadIdx.x;
  __shared__ __align__(16) float alds[Tn + 64];   // +pad: tail prefetch safe

  if (blockIdx.x < Bn) {
    // ---------------- producer: serial scan for row b ----------------
    __builtin_amdgcn_s_setprio(3);
    const int b = blockIdx.x;
    {  // stage row -> LDS, coalesced (one-time cost, outside the chain)
      const float4* __restrict__ arow =
          reinterpret_cast<const float4*>(alphas + (size_t)b * Tn);
      for (int i = lane; i < Tn / 4; i += 64)
        *reinterpret_cast<float4*>(&alds[4 * i]) = arow[i];
      for (int i = Tn / 4 + lane; i < (Tn + 64) / 4; i += 64)
        *reinterpret_cast<float4*>(&alds[4 * i]) =
            make_float4(0.f, 0.f, 0.f, 0.f);
    }
    __syncthreads();

    const float4* __restrict__ lds4 =
        reinterpret_cast<const float4*>(&alds[0]);
    float I  = 0.0f;
    int   fc = 0;

    float4 q0 = lds4[0], q1 = lds4[1], q2 = lds4[2], q3 = lds4[3],
           q4 = lds4[4];
    int rd = 5;

    auto step4 = [&](const float4& q) {
#pragma unroll
      for (int j = 0; j < 4; ++j) {
        const float a = (j == 0) ? q.x : (j == 1) ? q.y : (j == 2) ? q.z : q.w;
        const float integ = I + a;            // reference op order
        const bool  fire  = integ > kThresh;
        I  = fire ? (integ - 1.0f) : integ;
        fc += fire ? 1 : 0;
      }
    };

    for (int c = 0; c < 100; ++c) {           // 20 steps per iteration
      if (lane == 0 && (c & 1) == 0) {        // state at t = 20c -> chunk c/2
        const uint64_t v = ((uint64_t)__float_as_uint(I) << 32) |
                           (uint64_t)(PUBF | (unsigned)fc);
        __hip_atomic_store(&meta[(size_t)b * MSTRIDE + (c >> 1)], v,
                           __ATOMIC_RELAXED, __HIP_MEMORY_SCOPE_AGENT);
      }
      step4(q0); q0 = lds4[rd + 0];           // reload right after consume
      step4(q1); q1 = lds4[rd + 1];
      step4(q2); q2 = lds4[rd + 2];
      step4(q3); q3 = lds4[rd + 3];
      step4(q4); q4 = lds4[rd + 4];
      rd += 5;
    }
    return;
  }

  // ---------------- consumer: (chunk tc, row b, quarter) ----------------
  const int idx  = blockIdx.x - Bn;
  const int b    = idx & (Bn - 1);
  const int q    = idx >> 5;                // 0..NTCH*CSPLIT-1, low q first
  const int tc   = q >> 2;                  // low blockIdx -> low tc
  const int quar = q & 3;
  const int t_start = tc * TCHUNK;
  const int col  = quar * (Hn / CSPLIT) + lane * 2;   // float2 per lane

  auto wait_meta = [&](int c) -> uint64_t {
    const uint64_t* p = &meta[(size_t)b * MSTRIDE + c];
    uint64_t v;
    for (;;) {
      v = __hip_atomic_load(p, __ATOMIC_RELAXED, __HIP_MEMORY_SCOPE_AGENT);
      if ((unsigned)v & PUBF) break;
      __builtin_amdgcn_s_sleep(16);
    }
    return v;
  };

  const float* __restrict__ arow = alphas + (size_t)b * Tn;

  // Chunk-start state (bit-exact from producer).
  float I; int s;
  if (tc == 0) { I = 0.0f; s = 0; }
  else {
    const uint64_t v = wait_meta(tc);
    I = __uint_as_float((unsigned)(v >> 32));
    s = (int)((unsigned)v & 0xFFFFu);
  }

  // Walk back: find t_prev (last fire before t_start) and its remainder.
  int   t_prev   = -1;
  float rem_prev = 0.0f;
  for (int k = 1; tc - k >= 0 && t_prev < 0; ++k) {
    const int ck = tc - k;
    float Ik;
    if (ck == 0) Ik = 0.0f;
    else {
      const uint64_t v = wait_meta(ck);
      Ik = __uint_as_float((unsigned)(v >> 32));
    }
    const float* __restrict__ ap = arow + ck * TCHUNK;
    int lt = -1; float lrem = 0.0f;
#pragma unroll
    for (int j = 0; j < TCHUNK; ++j) {
      const float a     = ap[j];               // uniform scalar load
      const float integ = Ik + a;              // reference op order
      const bool  fire  = integ > kThresh;
      if (fire) { lt = ck * TCHUNK + j; lrem = a - (1.0f - Ik); }
      Ik = fire ? (integ - 1.0f) : integ;
    }
    if (lt >= 0) { t_prev = lt; rem_prev = lrem; }
  }

  const float* __restrict__ hb = hidden + (size_t)b * Tn * Hn + col;
  float2 acc = make_float2(0.f, 0.f);

  auto loadh = [&](int t) -> float2 {
    return *reinterpret_cast<const float2*>(hb + (size_t)t * Hn);
  };

  if (t_prev >= 0) {            // opening: frame = rem * h[t_prev]
    const float2 h = loadh(t_prev);
    acc.x = rem_prev * h.x; acc.y = rem_prev * h.y;
  }
  for (int t = t_prev + 1; t < t_start; ++t) {   // straddler interior rows
    const float a  = arow[t];
    const float2 h = loadh(t);
    acc.x += a * h.x; acc.y += a * h.y;
  }

  // Replay chunk tc with depth-4 h prefetch; close/store owned segments.
  float2 p0 = loadh(t_start);
  float2 p1 = loadh(t_start + 1);
  float2 p2 = loadh(t_start + 2);
  float2 p3 = loadh(t_start + 3);
  for (int j = 0; j < TCHUNK; ++j) {
    const int t   = t_start + j;
    const int tpf = t_start + ((j + 4 < TCHUNK) ? j + 4 : TCHUNK - 1);
    const float2 pn = loadh(tpf);            // issue BEFORE consuming p0
    const float a     = arow[t];             // uniform scalar load
    const float integ = I + a;               // reference op order
    const bool  fire  = integ > kThresh;     // wave-uniform
    if (fire) {
      const float cw = 1.0f - I;             // dist_completion
      acc.x += cw * p0.x; acc.y += cw * p0.y;
      if (s < Ln) {
        float* op = out + ((size_t)b * Ln + s) * Hn + col;
        *reinterpret_cast<float2*>(op) = acc;
      }
      const float rem = a - cw;              // remainds -> opens next segment
      acc.x = rem * p0.x; acc.y = rem * p0.y;
      s += 1;
      I  = integ - 1.0f;
    } else {
      acc.x += a * p0.x; acc.y += a * p0.y;
      I = integ;
    }
    p0 = p1; p1 = p2; p2 = p3; p3 = pn;
  }
  // Open tail is owned by consumer (tc+1); nothing more to store...
  if (tc == NTCH - 1) {                      // ...except zero-fill at the end
    const float2 z = make_float2(0.f, 0.f);
    for (int s2 = s; s2 < Ln; ++s2) {
      float* op = out + ((size_t)b * Ln + s2) * Hn + col;
      *reinterpret_cast<float2*>(op) = z;
    }
  }
}

extern "C" void kernel_launch(void* const* d_in, const int* in_sizes, int n_in,
                              void* d_out, int out_size, void* d_ws, size_t ws_size,
                              hipStream_t stream) {
  const float* hidden = (const float*)d_in[0];
  const float* alphas = (const float*)d_in[1];
  float* out = (float*)d_out;

  // ws layout: meta[Bn*MSTRIDE] u64 (16 KB, memset each call -- poison 0xAA
  // would read as published since bit30 of 0xAAAAAAAA is set).
  uint64_t* meta = (uint64_t*)d_ws;
  hipMemsetAsync(meta, 0, (size_t)Bn * MSTRIDE * sizeof(uint64_t), stream);

  const int nblocks = Bn + NTCH * Bn * CSPLIT;  // 32 producers + 6400 consumers
  cif_fused_kernel<<<nblocks, 64, 0, stream>>>(hidden, alphas, meta, out);
}